// Round 6
// baseline (7708.282 us; speedup 1.0000x reference)
//
#include <hip/hip_runtime.h>
#include <hip/hip_bf16.h>

#define B_   32
#define T_   512
#define NN_  16
#define CV_  150
#define D_   512
#define H_   512
#define BT_  16384      // B*T
#define K0_  1024       // 2*D
#define G3H_ 1536       // 3*H
#define SUBS_ 32        // blocks per layer in fused kernel
#define NBF_ 160        // 5 * SUBS_
#define WSZ_ 49152      // bf16 elems of swizzled W per block (96 frags * 512)
#define FS_  520        // stage_s frag stride in u16 (512 + 8 pad)

using bf16x8 = __attribute__((ext_vector_type(8))) short;
using f32x4  = __attribute__((ext_vector_type(4))) float;
using u32x4  = __attribute__((ext_vector_type(4))) unsigned int;
typedef unsigned long long u64;

__device__ __forceinline__ unsigned short f2bf(float f){
  unsigned int u = __builtin_bit_cast(unsigned int, f);
  u += 0x7fffu + ((u >> 16) & 1u);           // RNE
  return (unsigned short)(u >> 16);
}

__device__ __forceinline__ void store8(unsigned short* p, f32x4 a, f32x4 b){
  union { unsigned short us[8]; u32x4 v; } u;
  u.us[0]=f2bf(a[0]); u.us[1]=f2bf(a[1]); u.us[2]=f2bf(a[2]); u.us[3]=f2bf(a[3]);
  u.us[4]=f2bf(b[0]); u.us[5]=f2bf(b[1]); u.us[6]=f2bf(b[2]); u.us[7]=f2bf(b[3]);
  *(u32x4*)p = u.v;
}

// coherent (L3-level) helpers: relaxed agent-scope atomics -> sc0/sc1, NO fences
__device__ __forceinline__ u64 ld_coh_u64(const u64* p){
  return __hip_atomic_load(p, __ATOMIC_RELAXED, __HIP_MEMORY_SCOPE_AGENT);
}
__device__ __forceinline__ void st_coh_u64s(u64* p, u64 v){
  __hip_atomic_store(p, v, __ATOMIC_RELAXED, __HIP_MEMORY_SCOPE_AGENT);
}
__device__ __forceinline__ void st_flag(int* p, int v){
  __hip_atomic_store(p, v, __ATOMIC_RELAXED, __HIP_MEMORY_SCOPE_AGENT);
}
__device__ __forceinline__ int ld_flag(const int* p){
  return __hip_atomic_load(p, __ATOMIC_RELAXED, __HIP_MEMORY_SCOPE_AGENT);
}

// ---------------- fp32 -> bf16 weight conversion ----------------
__global__ void convert_bf16(const float* __restrict__ src,
                             unsigned short* __restrict__ dst, int n){
  int i = blockIdx.x * 256 + threadIdx.x;
  if (i < n) dst[i] = f2bf(src[i]);
}

// ---------------- swizzle W into MFMA A-frag layout ----------------
// wsw[blk=l*32+sub][fragl=g*32+ks][lam*8+e] ; ks<16 = Whh kstep, ks>=16 = Wih kstep
// row = g*512 + sub*16 + (lam&15); k = (ks&15)*32 + (lam>>4)*8 + e
__global__ void prep_wfrag(const float* __restrict__ whh0,
                           const float* __restrict__ whhr,
                           const float* __restrict__ wihr,
                           unsigned short* __restrict__ wsw, int total){
  int idx = blockIdx.x * 256 + threadIdx.x;
  if (idx >= total) return;
  int pos = idx & 511;
  int lam = pos >> 3, e = pos & 7;
  int fr  = idx >> 9;
  int ks  = fr & 31;
  int g   = (fr >> 5) % 3;
  int blk = fr / 96;
  int sub = blk & 31, l = blk >> 5;
  int row = g * 512 + sub * 16 + (lam & 15);
  int k   = (ks & 15) * 32 + (lam >> 4) * 8 + e;
  float v;
  if (l == 0) v = (ks < 16) ? whh0[(size_t)row * H_ + k] : 0.f;
  else {
    const float* w = (ks < 16) ? (whhr + (size_t)(l - 1) * G3H_ * H_)
                               : (wihr + (size_t)(l - 1) * G3H_ * H_);
    v = w[(size_t)row * H_ + k];
  }
  wsw[idx] = f2bf(v);
}

// bias_sw[blk][u][q]: q=0 r-bias, 1 z-bias, 2 xn-bias(bih_n), 3 hn-bias(bhh_n)
__global__ void prep_bias(const float* __restrict__ bhh0,
                          const float* __restrict__ bihr,
                          const float* __restrict__ bhhr,
                          float* __restrict__ bias_sw, int total){
  int idx = blockIdx.x * 256 + threadIdx.x;
  if (idx >= total) return;
  int q = idx & 3, u = (idx >> 2) & 15, sub = (idx >> 6) & 31, l = idx >> 11;
  int j = sub * 16 + u;
  float v;
  if (l == 0){
    v = (q == 0) ? bhh0[j] : (q == 1) ? bhh0[512 + j] : (q == 2) ? 0.f : bhh0[1024 + j];
  } else {
    const float* bi = bihr + (size_t)(l - 1) * G3H_;
    const float* bh = bhhr + (size_t)(l - 1) * G3H_;
    v = (q == 0) ? bi[j] + bh[j]
      : (q == 1) ? bi[512 + j] + bh[512 + j]
      : (q == 2) ? bi[1024 + j] : bh[1024 + j];
  }
  bias_sw[idx] = v;
}

// ---------------- embeddings ----------------
__global__ __launch_bounds__(64) void emb_kernel(
    const int* __restrict__ note, const int* __restrict__ chord,
    const float* __restrict__ ctab, const float* __restrict__ ntab,
    unsigned short* __restrict__ x0){
  const int bt = blockIdx.x;
  const int tid = threadIdx.x;
  __shared__ int sn[NN_];
  if (tid < NN_) sn[tid] = note[bt * NN_ + tid];
  __syncthreads();
  float alive = 1.f, cnt = 0.f;
  float msk[NN_];
  #pragma unroll
  for (int k = 0; k < NN_; ++k){ if (sn[k] == 0) alive = 0.f; msk[k] = alive; cnt += alive; }
  const float inv = 1.f / fmaxf(cnt, 1.f);
  const int ch = chord[bt];
  const int d0 = tid * 8;
  f32x4 c0 = {0.f,0.f,0.f,0.f}, c1 = {0.f,0.f,0.f,0.f};
  if (ch != 0){
    const float* cp = ctab + (size_t)ch * D_ + d0;
    c0 = *(const f32x4*)cp; c1 = *(const f32x4*)(cp + 4);
  }
  f32x4 s0 = {0.f,0.f,0.f,0.f}, s1 = {0.f,0.f,0.f,0.f};
  #pragma unroll
  for (int k = 0; k < NN_; ++k){
    if (msk[k] != 0.f){
      const float* np = ntab + (size_t)sn[k] * D_ + d0;
      s0 += *(const f32x4*)np;
      s1 += *(const f32x4*)(np + 4);
    }
  }
  s0 *= inv; s1 *= inv;
  unsigned short* o = x0 + (size_t)bt * K0_ + d0;
  store8(o, c0, c1);
  store8(o + D_, s0, s1);
}

// ---------------- bf16 MFMA GEMM:  Y = X[M,K] @ W[N,K]^T + bias ----------------
__global__ __launch_bounds__(256) void gemm_bt(
    const unsigned short* __restrict__ X, const unsigned short* __restrict__ W,
    const float* __restrict__ bias, float* __restrict__ Y,
    int M, int N, int K, int wmode){
  const int lane = threadIdx.x & 63;
  const int wave = threadIdx.x >> 6;
  const int l15 = lane & 15, kq4 = lane >> 4;
  const int m_frag = blockIdx.y * 64 + wave * 16 + l15;
  const int n_base = blockIdx.x * 64;
  f32x4 acc[4] = {{0.f,0.f,0.f,0.f},{0.f,0.f,0.f,0.f},{0.f,0.f,0.f,0.f},{0.f,0.f,0.f,0.f}};
  const unsigned short* xptr = X + (size_t)m_frag * K + kq4 * 8;
  const unsigned short* wptr[4];
  #pragma unroll
  for (int i = 0; i < 4; ++i){
    int n = n_base + i * 16 + l15;
    if (n >= N) n = N - 1;
    wptr[i] = W + (size_t)n * K + kq4 * 8;
  }
  for (int k0 = 0; k0 < K; k0 += 32){
    bf16x8 a = *(const bf16x8*)(xptr + k0);
    #pragma unroll
    for (int i = 0; i < 4; ++i){
      bf16x8 b = *(const bf16x8*)(wptr[i] + k0);
      acc[i] = __builtin_amdgcn_mfma_f32_16x16x32_bf16(a, b, acc[i], 0, 0, 0);
    }
  }
  const int mrow = blockIdx.y * 64 + wave * 16 + kq4 * 4;
  #pragma unroll
  for (int i = 0; i < 4; ++i){
    int n = n_base + i * 16 + l15;
    if (n < N){
      float bv = bias[n];
      #pragma unroll
      for (int r = 0; r < 4; ++r){
        int m = mrow + r;
        float v = acc[i][r] + bv;
        if (wmode == 0) Y[(size_t)m * N + n] = v;
        else            Y[((size_t)(m & (T_-1)) * N + n) * B_ + (m >> 9)] = v;
      }
    }
  }
}

// ---------------- fused 5-layer pipelined GRU: tag-validated transport ----------------
// hT: u32[5][4 slots][32 batch][512 unit]; value = (h_bf16<<16)|tag; tag(h(s)) = s+1.
//     h(t) lives in slot t&3. Written at step t-1 (init writes h(0), tag 1).
// xT: u32[4][4 slots][32][512]; x(t)=y_l(t), tag t+1, slot t&3.
// Back-pressure (rare spins): flags[l*64+sub] = steps whose STAGES are complete.
//   write h(t+1): own-layer peers >= t-2 ; write x(t): consumer layer >= t-3.
__global__ __launch_bounds__(256, 1) void gru_fused(
    const float* __restrict__ xp, const unsigned short* __restrict__ wsw,
    const float* __restrict__ bias_sw, unsigned int* __restrict__ hT,
    unsigned int* __restrict__ xT, unsigned short* __restrict__ xout,
    int* __restrict__ flags){
  __shared__ unsigned short w_s[96 * 512];     // 96 KB A-frags
  __shared__ unsigned short stage_s[32 * FS_]; // ~33 KB B-frags (h, then x)
  __shared__ float p_s[4][2][16][16];          // 8 KB partials

  const int tid = threadIdx.x;
  const int blk = blockIdx.x;
  const int l   = blk >> 5;
  const int sub = blk & 31;
  const int lane = tid & 63, wave = tid >> 6;
  const int l15 = lane & 15, l4 = lane >> 4;
  const int myn = wave >> 1;
  const bool rzw = (wave & 1) == 0;

  {
    const u32x4* src = (const u32x4*)(wsw + (size_t)blk * WSZ_);
    u32x4* dst = (u32x4*)w_s;
    #pragma unroll
    for (int i = 0; i < 24; ++i) dst[tid + 256 * i] = src[tid + 256 * i];
  }

  const int cb = tid & 31;
  const int cj = (tid >> 5) * 2;
  const int jg = sub * 16 + cj;
  const float* bsp = bias_sw + blk * 64;
  const float br0 = bsp[cj*4+0],     bz0 = bsp[cj*4+1],     bx0 = bsp[cj*4+2],     bn0 = bsp[cj*4+3];
  const float br1 = bsp[(cj+1)*4+0], bz1 = bsp[(cj+1)*4+1], bx1 = bsp[(cj+1)*4+2], bn1 = bsp[(cj+1)*4+3];
  float hres0 = 0.f, hres1 = 0.f;

  unsigned int* hTl = hT + (size_t)l * (4 * 32 * 512);
  unsigned int* xTw = xT + (size_t)l * (4 * 32 * 512);                   // l<4
  const unsigned int* xTr = xT + (size_t)(l - 1) * (4 * 32 * 512);       // l>0
  int*       fl_own  = flags + l * 64;
  const int* fl_cons = flags + (l < 4 ? (l + 1) * 64 : l * 64);

  // init h(0): slot 0, h=0, tag=1 (each block covers its own 16 units x 32 batches)
  st_coh_u64s((u64*)&hTl[(size_t)cb * 512 + jg], 0x0000000100000001ull);

  // staging constants: per (i 0..7): b = bl_|((i&1)<<4), u64 idx d = b*256 + qh_ + (i>>1)*64 + j
  const int bl_ = tid & 15;
  const int qh_ = ((tid >> 4) & 15) * 4;
  const int wv_ = tid >> 6;
  const int lanef_ = ((tid >> 4) & 3) * 16 + (tid & 15);

  auto issue32 = [&](const u64* sbase, u64 (&v)[8][4]){
    #pragma unroll
    for (int i = 0; i < 8; ++i){
      const u64* sp = sbase + ((size_t)(bl_ | ((i & 1) << 4)) << 8) + qh_ + ((i >> 1) << 6);
      #pragma unroll
      for (int j = 0; j < 4; ++j) v[i][j] = ld_coh_u64(sp + j);
    }
  };
  auto finish32 = [&](const u64* sbase, u64 (&v)[8][4], u64 wantp){
    while (true){
      unsigned bad = 0;
      #pragma unroll
      for (int i = 0; i < 8; ++i)
        #pragma unroll
        for (int j = 0; j < 4; ++j)
          if ((v[i][j] & 0x0000FFFF0000FFFFull) != wantp) bad |= 1u << (i * 4 + j);
      if (!bad) break;
      __builtin_amdgcn_s_sleep(1);
      #pragma unroll
      for (int i = 0; i < 8; ++i){
        const u64* sp = sbase + ((size_t)(bl_ | ((i & 1) << 4)) << 8) + qh_ + ((i >> 1) << 6);
        #pragma unroll
        for (int j = 0; j < 4; ++j)
          if ((bad >> (i * 4 + j)) & 1) v[i][j] = ld_coh_u64(sp + j);
      }
    }
    #pragma unroll
    for (int i = 0; i < 8; ++i){
      int f = ((i & 1) << 4) + ((i >> 1) << 2) + wv_;
      u32x4 o;
      #pragma unroll
      for (int j = 0; j < 4; ++j)
        o[j] = (unsigned)((v[i][j] >> 16) & 0xFFFFu)
             | (unsigned)((v[i][j] >> 32) & 0xFFFF0000u);
      *(u32x4*)&stage_s[(size_t)f * FS_ + (size_t)lanef_ * 8] = o;
    }
  };

  __syncthreads();   // W ready

  for (int t = 0; t < T_; ++t){
    // ---- back-pressure guard (slack 2/3 steps; rarely spins) ----
    if (wave == 0){
      const int* pp; int tgt;
      if (lane < 32){ pp = fl_own + lane; tgt = t - 2; }
      else { pp = fl_cons + (lane - 32); tgt = (l < 4) ? (t - 3) : (-(1 << 30)); }
      int vv = ld_flag(pp);
      while (!__all(vv >= tgt)){ __builtin_amdgcn_s_sleep(1); vv = ld_flag(pp); }
    }

    const unsigned want = (unsigned)(t + 1);
    const u64 wantp = (u64)want | ((u64)want << 32);

    // layer-0 input projection (plain cached loads; overlap with staging)
    float er = 0.f, ez = 0.f, en = 0.f, er1 = 0.f, ez1 = 0.f, en1 = 0.f;
    if (l == 0){
      const float* xb = xp + (size_t)t * (G3H_ * B_) + cb;
      er  = xb[(size_t)(0 * H_ + jg) * B_];  er1 = xb[(size_t)(0 * H_ + jg + 1) * B_];
      ez  = xb[(size_t)(1 * H_ + jg) * B_];  ez1 = xb[(size_t)(1 * H_ + jg + 1) * B_];
      en  = xb[(size_t)(2 * H_ + jg) * B_];  en1 = xb[(size_t)(2 * H_ + jg + 1) * B_];
    }

    // ---- phase A: stage h(t) (tag-validated) ----
    const u64* hbase = (const u64*)(hTl + (size_t)(t & 3) * (32 * 512));
    u64 vh[8][4], vx[8][4];
    issue32(hbase, vh);
    finish32(hbase, vh, wantp);
    __syncthreads();                               // S1: h B-frags ready

    // issue x loads early so the L3 round trip hides under the h-MFMAs
    const u64* xbase = (const u64*)(xTr + (size_t)(t & 3) * (32 * 512));
    if (l > 0) issue32(xbase, vx);

    // ---- MFMA: h part (ks 0..15) ----
    f32x4 accA = {0.f,0.f,0.f,0.f}, accB = {0.f,0.f,0.f,0.f};
    #pragma unroll
    for (int ks = 0; ks < 16; ++ks){
      bf16x8 b = *(const bf16x8*)&stage_s[(size_t)((myn << 4) + ks) * FS_ + lane * 8];
      if (rzw){
        bf16x8 a0 = *(const bf16x8*)&w_s[(0 * 32 + ks) * 512 + lane * 8];
        bf16x8 a1 = *(const bf16x8*)&w_s[(1 * 32 + ks) * 512 + lane * 8];
        accA = __builtin_amdgcn_mfma_f32_16x16x32_bf16(a0, b, accA, 0, 0, 0);
        accB = __builtin_amdgcn_mfma_f32_16x16x32_bf16(a1, b, accB, 0, 0, 0);
      } else {
        bf16x8 a2 = *(const bf16x8*)&w_s[(2 * 32 + ks) * 512 + lane * 8];
        accA = __builtin_amdgcn_mfma_f32_16x16x32_bf16(a2, b, accA, 0, 0, 0);
      }
    }
    // ---- phase B: stage x(t), then x-MFMAs (ks 16..31) ----
    if (l > 0){
      __syncthreads();                             // S2: h B-frag reads done
      finish32(xbase, vx, wantp);
      __syncthreads();                             // S3: x B-frags ready
      #pragma unroll
      for (int ks = 0; ks < 16; ++ks){
        bf16x8 b = *(const bf16x8*)&stage_s[(size_t)((myn << 4) + ks) * FS_ + lane * 8];
        if (rzw){
          bf16x8 a0 = *(const bf16x8*)&w_s[(0 * 32 + 16 + ks) * 512 + lane * 8];
          bf16x8 a1 = *(const bf16x8*)&w_s[(1 * 32 + 16 + ks) * 512 + lane * 8];
          accA = __builtin_amdgcn_mfma_f32_16x16x32_bf16(a0, b, accA, 0, 0, 0);
          accB = __builtin_amdgcn_mfma_f32_16x16x32_bf16(a1, b, accB, 0, 0, 0);
        } else {
          bf16x8 a2 = *(const bf16x8*)&w_s[(2 * 32 + 16 + ks) * 512 + lane * 8];
          accB = __builtin_amdgcn_mfma_f32_16x16x32_bf16(a2, b, accB, 0, 0, 0);  // xn
        }
      }
    }
    // stages of step t complete -> post progress (enables peer/producer overwrites)
    if (tid == 0) st_flag(fl_own + sub, t + 1);

    // ---- accs -> p_s ----
    #pragma unroll
    for (int r = 0; r < 4; ++r){
      int u = l4 * 4 + r;
      if (rzw){ p_s[0][myn][u][l15] = accA[r]; p_s[1][myn][u][l15] = accB[r]; }
      else    { p_s[2][myn][u][l15] = accA[r]; p_s[3][myn][u][l15] = accB[r]; }
    }
    __syncthreads();                               // S4

    // ---- combine: gates + state update + tagged stores ----
    {
      const int nt = cb >> 4, bc = cb & 15;
      float rp0 = p_s[0][nt][cj][bc],     rp1 = p_s[0][nt][cj + 1][bc];
      float zp0 = p_s[1][nt][cj][bc],     zp1 = p_s[1][nt][cj + 1][bc];
      float hp0 = p_s[2][nt][cj][bc],     hp1 = p_s[2][nt][cj + 1][bc];
      float xq0 = p_s[3][nt][cj][bc],     xq1 = p_s[3][nt][cj + 1][bc];
      float r0 = 1.f / (1.f + __expf(-(rp0 + er  + br0)));
      float r1 = 1.f / (1.f + __expf(-(rp1 + er1 + br1)));
      float z0 = 1.f / (1.f + __expf(-(zp0 + ez  + bz0)));
      float z1 = 1.f / (1.f + __expf(-(zp1 + ez1 + bz1)));
      float nx0 = (l > 0) ? (xq0 + bx0) : en;
      float nx1 = (l > 0) ? (xq1 + bx1) : en1;
      float e0 = __expf(2.f * (nx0 + r0 * (hp0 + bn0)));
      float e1 = __expf(2.f * (nx1 + r1 * (hp1 + bn1)));
      float n0 = (e0 - 1.f) / (e0 + 1.f);
      float n1 = (e1 - 1.f) / (e1 + 1.f);
      float h0 = (1.f - z0) * n0 + z0 * hres0; hres0 = h0;
      float h1 = (1.f - z1) * n1 + z1 * hres1; hres1 = h1;
      unsigned hb0 = f2bf(h0), hb1 = f2bf(h1);
      u64 hv = ((u64)((hb1 << 16) | (unsigned)(t + 2)) << 32)
             |  (u64)((hb0 << 16) | (unsigned)(t + 2));
      st_coh_u64s((u64*)&hTl[(size_t)((t + 1) & 3) * (32 * 512) + cb * 512 + jg], hv);
      if (l < 4){
        u64 xv = ((u64)((hb1 << 16) | want) << 32)
               |  (u64)((hb0 << 16) | want);
        st_coh_u64s((u64*)&xTw[(size_t)(t & 3) * (32 * 512) + cb * 512 + jg], xv);
      } else {
        *(unsigned int*)&xout[((size_t)cb * T_ + t) * H_ + jg] = hb0 | (hb1 << 16);
      }
    }
    // no end-of-step barrier needed: tags order the data; S1 of t+1 orders LDS reuse
  }
}

extern "C" void kernel_launch(void* const* d_in, const int* in_sizes, int n_in,
                              void* d_out, int out_size, void* d_ws, size_t ws_size,
                              hipStream_t stream){
  (void)in_sizes; (void)n_in; (void)out_size; (void)ws_size;
  const int*   note  = (const int*)d_in[0];
  const int*   chord = (const int*)d_in[1];
  const float* ctab  = (const float*)d_in[2];
  const float* ntab  = (const float*)d_in[3];
  const float* wih0  = (const float*)d_in[4];
  const float* whh0  = (const float*)d_in[5];
  const float* bih0  = (const float*)d_in[6];
  const float* bhh0  = (const float*)d_in[7];
  const float* wihr  = (const float*)d_in[8];
  const float* whhr  = (const float*)d_in[9];
  const float* bihr  = (const float*)d_in[10];
  const float* bhhr  = (const float*)d_in[11];
  const float* fcw   = (const float*)d_in[12];
  const float* fcb   = (const float*)d_in[13];
  float* out = (float*)d_out;

  char* ws = (char*)d_ws;
  size_t off = 0;
  auto alloc = [&](size_t bytes)->char*{
    char* p = ws + off; off = (off + bytes + 255) & ~(size_t)255; return p;
  };
  int*            flags   = (int*)alloc((size_t)5 * 64 * sizeof(int));
  float*          xp      = (float*)alloc((size_t)BT_ * G3H_ * 4);
  unsigned short* x0      = (unsigned short*)alloc((size_t)BT_ * K0_ * 2);
  unsigned short* xout    = (unsigned short*)alloc((size_t)BT_ * H_ * 2);
  unsigned int*   hT      = (unsigned int*)alloc((size_t)5 * 4 * 32 * 512 * 4);
  unsigned int*   xT      = (unsigned int*)alloc((size_t)4 * 4 * 32 * 512 * 4);
  unsigned short* wsw     = (unsigned short*)alloc((size_t)NBF_ * WSZ_ * 2);
  float*          bias_sw = (float*)alloc((size_t)NBF_ * 64 * 4);
  unsigned short* wih0_b  = (unsigned short*)alloc((size_t)G3H_ * K0_ * 2);
  unsigned short* fcw_b   = (unsigned short*)alloc((size_t)CV_ * H_ * 2);

  // zero flags + tag arrays (tag 0 never matches any want >= 1); runs every launch,
  // so graph replay and poisoned/garbage workspace are both safe.
  hipMemsetAsync(flags, 0, (size_t)5 * 64 * sizeof(int), stream);
  hipMemsetAsync(hT, 0, (size_t)5 * 4 * 32 * 512 * 4, stream);
  hipMemsetAsync(xT, 0, (size_t)4 * 4 * 32 * 512 * 4, stream);

  { int n = G3H_ * K0_; convert_bf16<<<(n + 255) / 256, 256, 0, stream>>>(wih0, wih0_b, n); }
  { int n = CV_ * H_;   convert_bf16<<<(n + 255) / 256, 256, 0, stream>>>(fcw, fcw_b, n); }
  { int n = NBF_ * WSZ_;
    prep_wfrag<<<(n + 255) / 256, 256, 0, stream>>>(whh0, whhr, wihr, wsw, n); }
  { int n = NBF_ * 64;
    prep_bias<<<(n + 255) / 256, 256, 0, stream>>>(bhh0, bihr, bhhr, bias_sw, n); }

  emb_kernel<<<BT_, 64, 0, stream>>>(note, chord, ctab, ntab, x0);

  // layer-0 input projection: xp = x0 @ wih0^T + bih0, layout [T][3H][B]
  gemm_bt<<<dim3(G3H_ / 64, BT_ / 64), 256, 0, stream>>>(x0, wih0_b, bih0, xp, BT_, G3H_, K0_, 1);

  // fused 5-layer pipelined recurrence (tag-validated transport, no barriers)
  gru_fused<<<NBF_, 256, 0, stream>>>(xp, wsw, bias_sw, hT, xT, xout, flags);

  // FC: out = xout @ fcw^T + fcb
  gemm_bt<<<dim3((CV_ + 63) / 64, BT_ / 64), 256, 0, stream>>>(
      xout, fcw_b, fcb, out, BT_, CV_, H_, 0);
}